// Round 18
// baseline (1171.225 us; speedup 1.0000x reference)
//
#include <hip/hip_runtime.h>
#include <hip/hip_bf16.h>
#include <math.h>

#define L_ 4
#define D_ 512
#define H_ 8
#define T_ 1024
#define B_ 8
#define FF_ 2048
#define EC_ 1024
#define KW_ 31
#define DH_ 64
#define ROWS (B_*T_)   // 8192

typedef __attribute__((ext_vector_type(8))) short short8;
typedef __attribute__((ext_vector_type(4))) float f32x4;
typedef __attribute__((ext_vector_type(4))) unsigned short ushort4v;
typedef __attribute__((ext_vector_type(2))) unsigned short ushort2v;

static __device__ __forceinline__ unsigned short f2bf(float f) {
  __hip_bfloat16 h = __float2bfloat16(f);   // native RNE cvt
  unsigned short u;
  __builtin_memcpy(&u, &h, 2);
  return u;
}
static __device__ __forceinline__ float bf2f(unsigned short h) {
  union { unsigned u; float f; } v; v.u = ((unsigned)h) << 16;
  return v.f;
}
static __device__ __forceinline__ float sigm(float x) {
  return __builtin_amdgcn_rcpf(1.0f + __expf(-x));
}

#define GLDS(gp, lp) __builtin_amdgcn_global_load_lds( \
    (const __attribute__((address_space(1))) unsigned int*)(const void*)(gp), \
    (__attribute__((address_space(3))) unsigned int*)(void*)(lp), 16, 0, 0)

// 8-slot-per-row XOR swizzle (rows of 8x16B)
#define SW8(row, slot) ((slot) ^ (((row) ^ ((row) >> 3)) & 7))

// ---------------------------------------------------------------- fused f32->bf16 convert + LayerNorm
__global__ __launch_bounds__(256) void cvt_ln_kernel(const float* __restrict__ in,
    const float* __restrict__ g, const float* __restrict__ b,
    unsigned short* __restrict__ x, unsigned short* __restrict__ y)
{
  int row = blockIdx.x * 4 + (threadIdx.x >> 6);
  int l = threadIdx.x & 63;
  const float* ir = in + (size_t)row * D_ + l * 8;
  float4 v0 = *(const float4*)ir;
  float4 v1 = *(const float4*)(ir + 4);
  float raw[8] = {v0.x, v0.y, v0.z, v0.w, v1.x, v1.y, v1.z, v1.w};
  short8 xo;
  float vv[8];
#pragma unroll
  for (int j = 0; j < 8; ++j) {
    unsigned short h = f2bf(raw[j]);
    xo[j] = (short)h;
    vv[j] = bf2f(h);
  }
  *(short8*)(x + (size_t)row * D_ + l * 8) = xo;
  float s = 0.f, s2 = 0.f;
#pragma unroll
  for (int j = 0; j < 8; ++j) { s += vv[j]; s2 += vv[j] * vv[j]; }
#pragma unroll
  for (int off = 32; off; off >>= 1) {
    s  += __shfl_xor(s,  off, 64);
    s2 += __shfl_xor(s2, off, 64);
  }
  float mean = s * (1.0f / D_);
  float var  = s2 * (1.0f / D_) - mean * mean;
  float r = __builtin_amdgcn_rsqf(var + 1e-5f);
  float4 g0 = *(const float4*)(g + l * 8);
  float4 g1 = *(const float4*)(g + l * 8 + 4);
  float4 b0 = *(const float4*)(b + l * 8);
  float4 b1 = *(const float4*)(b + l * 8 + 4);
  float gg[8] = {g0.x, g0.y, g0.z, g0.w, g1.x, g1.y, g1.z, g1.w};
  float bb[8] = {b0.x, b0.y, b0.z, b0.w, b1.x, b1.y, b1.z, b1.w};
  short8 o;
#pragma unroll
  for (int j = 0; j < 8; ++j) o[j] = (short)f2bf((vv[j] - mean) * r * gg[j] + bb[j]);
  *(short8*)(y + (size_t)row * D_ + l * 8) = o;
}

// ---------------------------------------------------------------- LayerNorm (bf16 in, bf16 out), wave/row
__global__ __launch_bounds__(256) void ln_bf16_kernel(const unsigned short* __restrict__ x,
    const float* __restrict__ g, const float* __restrict__ b, unsigned short* __restrict__ y)
{
  int row = blockIdx.x * 4 + (threadIdx.x >> 6);
  int l = threadIdx.x & 63;
  short8 xr = *(const short8*)(x + (size_t)row * D_ + l * 8);
  float vv[8];
#pragma unroll
  for (int j = 0; j < 8; ++j) vv[j] = bf2f((unsigned short)xr[j]);
  float s = 0.f, s2 = 0.f;
#pragma unroll
  for (int j = 0; j < 8; ++j) { s += vv[j]; s2 += vv[j] * vv[j]; }
#pragma unroll
  for (int off = 32; off; off >>= 1) {
    s  += __shfl_xor(s,  off, 64);
    s2 += __shfl_xor(s2, off, 64);
  }
  float mean = s * (1.0f / D_);
  float var  = s2 * (1.0f / D_) - mean * mean;
  float r = __builtin_amdgcn_rsqf(var + 1e-5f);
  float4 g0 = *(const float4*)(g + l * 8);
  float4 g1 = *(const float4*)(g + l * 8 + 4);
  float4 b0 = *(const float4*)(b + l * 8);
  float4 b1 = *(const float4*)(b + l * 8 + 4);
  float gg[8] = {g0.x, g0.y, g0.z, g0.w, g1.x, g1.y, g1.z, g1.w};
  float bb[8] = {b0.x, b0.y, b0.z, b0.w, b1.x, b1.y, b1.z, b1.w};
  short8 o;
#pragma unroll
  for (int j = 0; j < 8; ++j) o[j] = (short)f2bf((vv[j] - mean) * r * gg[j] + bb[j]);
  *(short8*)(y + (size_t)row * D_ + l * 8) = o;
}

// ---------------------------------------------------------------- dual LayerNorm (bf16 x)
template<bool BF2>
__global__ __launch_bounds__(256) void ln_dual_kernel(const unsigned short* __restrict__ x,
    const float* __restrict__ g1, const float* __restrict__ b1,
    const float* __restrict__ g2, const float* __restrict__ b2,
    unsigned short* __restrict__ y1, void* __restrict__ y2)
{
  int row = blockIdx.x * 4 + (threadIdx.x >> 6);
  int l = threadIdx.x & 63;
  short8 xr = *(const short8*)(x + (size_t)row * D_ + l * 8);
  float vv[8];
#pragma unroll
  for (int j = 0; j < 8; ++j) vv[j] = bf2f((unsigned short)xr[j]);
  float s = 0.f, s2 = 0.f;
#pragma unroll
  for (int j = 0; j < 8; ++j) { s += vv[j]; s2 += vv[j] * vv[j]; }
#pragma unroll
  for (int off = 32; off; off >>= 1) {
    s  += __shfl_xor(s,  off, 64);
    s2 += __shfl_xor(s2, off, 64);
  }
  float mean = s * (1.0f / D_);
  float var  = s2 * (1.0f / D_) - mean * mean;
  float r = __builtin_amdgcn_rsqf(var + 1e-5f);
  float4 g0 = *(const float4*)(g1 + l * 8);
  float4 g1v = *(const float4*)(g1 + l * 8 + 4);
  float4 b0 = *(const float4*)(b1 + l * 8);
  float4 b1v = *(const float4*)(b1 + l * 8 + 4);
  float ga[8] = {g0.x, g0.y, g0.z, g0.w, g1v.x, g1v.y, g1v.z, g1v.w};
  float ba[8] = {b0.x, b0.y, b0.z, b0.w, b1v.x, b1v.y, b1v.z, b1v.w};
  float yv[8];
  float u = 0.f, u2 = 0.f;
#pragma unroll
  for (int j = 0; j < 8; ++j) {
    yv[j] = (vv[j] - mean) * r * ga[j] + ba[j];
    u += yv[j]; u2 += yv[j] * yv[j];
  }
  {
    short8 o;
#pragma unroll
    for (int j = 0; j < 8; ++j) o[j] = (short)f2bf(yv[j]);
    *(short8*)(y1 + (size_t)row * D_ + l * 8) = o;
  }
#pragma unroll
  for (int off = 32; off; off >>= 1) {
    u  += __shfl_xor(u,  off, 64);
    u2 += __shfl_xor(u2, off, 64);
  }
  float mean2 = u * (1.0f / D_);
  float var2  = u2 * (1.0f / D_) - mean2 * mean2;
  float r2 = __builtin_amdgcn_rsqf(var2 + 1e-5f);
  float4 c0 = *(const float4*)(g2 + l * 8);
  float4 c1 = *(const float4*)(g2 + l * 8 + 4);
  float4 d0 = *(const float4*)(b2 + l * 8);
  float4 d1 = *(const float4*)(b2 + l * 8 + 4);
  float gc[8] = {c0.x, c0.y, c0.z, c0.w, c1.x, c1.y, c1.z, c1.w};
  float bc[8] = {d0.x, d0.y, d0.z, d0.w, d1.x, d1.y, d1.z, d1.w};
  if constexpr (BF2) {
    short8 o;
#pragma unroll
    for (int j = 0; j < 8; ++j) o[j] = (short)f2bf((yv[j] - mean2) * r2 * gc[j] + bc[j]);
    *(short8*)((unsigned short*)y2 + (size_t)row * D_ + l * 8) = o;
  } else {
    float z[8];
#pragma unroll
    for (int j = 0; j < 8; ++j) z[j] = (yv[j] - mean2) * r2 * gc[j] + bc[j];
    float4 o0 = {z[0], z[1], z[2], z[3]};
    float4 o1 = {z[4], z[5], z[6], z[7]};
    float* yp = (float*)y2 + (size_t)row * D_ + l * 8;
    *(float4*)yp = o0; *(float4*)(yp + 4) = o1;
  }
}

// ---------------------------------------------------------------- weight fp32[K][N] -> bf16[N][K]
__global__ __launch_bounds__(256) void wtr_kernel(const float* __restrict__ W,
    unsigned short* __restrict__ Wt, int K, int N)
{
  __shared__ float tile[32][33];
  const float* Wl = W + (size_t)blockIdx.z * K * N;
  unsigned short* Wtl = Wt + (size_t)blockIdx.z * K * N;
  int n0 = blockIdx.x * 32, k0 = blockIdx.y * 32;
  int c = threadIdx.x & 31, r = threadIdx.x >> 5;
#pragma unroll
  for (int it = 0; it < 4; ++it) {
    int kk = r + it * 8;
    tile[kk][c] = Wl[(size_t)(k0 + kk) * N + n0 + c];
  }
  __syncthreads();
#pragma unroll
  for (int it = 0; it < 4; ++it) {
    int nn = r + it * 8;
    Wtl[(size_t)(n0 + nn) * K + k0 + c] = f2bf(tile[c][nn]);
  }
}

// ---------------------------------------------------------------- bf16 MFMA GEMM (TM=128, BK=64)
// ring-2 LDS (64 KB), two-barrier iteration, 8 GLDS/tile/thread, XCD swizzle.
// EPI: 0=none->bf16[N], 1=silu->bf16[N],
//      2=residual->bf16[N]: C = bf16(bf2f(R)+alpha*(v)),
//      3=GLU: block covers 64 cols of BOTH halves of Wt; out=(a+ba)*sigm(g+bg), width N=EC_.
template<int EPI>
__global__ __launch_bounds__(256) void gemm_mfma(
    const unsigned short* __restrict__ A, const unsigned short* __restrict__ Wt,
    const float* __restrict__ bias, const unsigned short* __restrict__ R,
    void* __restrict__ Cv, int N, int K, float alpha)
{
  constexpr int AI = 4;
  __shared__ __align__(16) unsigned short As[2][128 * 64];   // 32 KB
  __shared__ __align__(16) unsigned short Bs[2][128 * 64];   // 32 KB
  int t = threadIdx.x;
  int gx = gridDim.x;
  int nwg = gx * gridDim.y;
  int orig = blockIdx.y * gx + blockIdx.x;
  int lg = (orig & 7) * (nwg >> 3) + (orig >> 3);
  int row0 = (lg / gx) * 128;
  int col0 = (lg % gx) * (EPI == 3 ? 64 : 128);
  int l = t & 63, w = t >> 6, wm = w >> 1, wn = w & 1;

  const unsigned short* agp[4];
  const unsigned short* bgp[4];
#pragma unroll
  for (int q = 0; q < 4; ++q) {
    int c = t + q * 256;
    int row = c >> 3, s = (c & 7) ^ (row & 7);
    agp[q] = A + (size_t)(row0 + row) * K + s * 8;
    int brow;
    if constexpr (EPI == 3)
      brow = (row < 64) ? (col0 + row) : (EC_ + col0 + (row - 64));
    else
      brow = col0 + row;
    bgp[q] = Wt + (size_t)brow * K + s * 8;
  }

  int lcol = l & 15, kq = l >> 4, lrow = kq * 4;
  int aoff[AI][2], boff[4][2];
#pragma unroll
  for (int i = 0; i < AI; ++i) {
    int row = wm * 64 + i * 16 + lcol;
#pragma unroll
    for (int kk = 0; kk < 2; ++kk)
      aoff[i][kk] = row * 64 + (((kk * 4 + kq) ^ (row & 7)) * 8);
  }
#pragma unroll
  for (int j = 0; j < 4; ++j) {
    int row;
    if constexpr (EPI == 3)
      row = (j < 2 ? wn * 32 + j * 16 : 64 + wn * 32 + (j - 2) * 16) + lcol;
    else
      row = wn * 64 + j * 16 + lcol;
#pragma unroll
    for (int kk = 0; kk < 2; ++kk)
      boff[j][kk] = row * 64 + (((kk * 4 + kq) ^ (row & 7)) * 8);
  }

  f32x4 acc[AI][4] = {};
  int nt = K >> 6;

  auto stage = [&](int buf) {
#pragma unroll
    for (int q = 0; q < 4; ++q) {
      GLDS(agp[q], As[buf] + (t + q * 256) * 8);
      GLDS(bgp[q], Bs[buf] + (t + q * 256) * 8);
      agp[q] += 64; bgp[q] += 64;
    }
  };
  stage(0); stage(1);

  for (int kt = 0; kt < nt; ++kt) {
    int cur = kt & 1;
    if (kt < nt - 1) asm volatile("s_waitcnt vmcnt(8)" ::: "memory");
    else             asm volatile("s_waitcnt vmcnt(0)" ::: "memory");
    __builtin_amdgcn_s_barrier();
    __builtin_amdgcn_sched_barrier(0);
    const unsigned short* Ab = As[cur];
    const unsigned short* Bb = Bs[cur];
    short8 af[AI][2], bfr[4][2];
#pragma unroll
    for (int i = 0; i < AI; ++i)
#pragma unroll
      for (int kk = 0; kk < 2; ++kk) af[i][kk] = *(const short8*)(Ab + aoff[i][kk]);
#pragma unroll
    for (int j = 0; j < 4; ++j)
#pragma unroll
      for (int kk = 0; kk < 2; ++kk) bfr[j][kk] = *(const short8*)(Bb + boff[j][kk]);
    __builtin_amdgcn_s_setprio(1);
#pragma unroll
    for (int kk = 0; kk < 2; ++kk)
#pragma unroll
      for (int i = 0; i < AI; ++i)
#pragma unroll
        for (int j = 0; j < 4; ++j)
          acc[i][j] = __builtin_amdgcn_mfma_f32_16x16x32_bf16(af[i][kk], bfr[j][kk],
                                                              acc[i][j], 0, 0, 0);
    __builtin_amdgcn_s_setprio(0);
    __builtin_amdgcn_s_barrier();
    __builtin_amdgcn_sched_barrier(0);
    if (kt + 2 < nt) stage(cur);
  }

  if constexpr (EPI == 3) {
    float bja[2], bjg[2];
#pragma unroll
    for (int j = 0; j < 2; ++j) {
      int c = col0 + wn * 32 + j * 16 + lcol;
      bja[j] = bias[c];
      bjg[j] = bias[EC_ + c];
    }
#pragma unroll
    for (int i = 0; i < AI; ++i) {
      int gr0 = row0 + wm * 64 + i * 16 + lrow;
#pragma unroll
      for (int j = 0; j < 2; ++j) {
        int gc = col0 + wn * 32 + j * 16 + lcol;
#pragma unroll
        for (int q = 0; q < 4; ++q) {
          float a = acc[i][j][q] + bja[j];
          float g = acc[i][j + 2][q] + bjg[j];
          ((unsigned short*)Cv)[(size_t)(gr0 + q) * N + gc] = f2bf(a * sigm(g));
        }
      }
    }
  } else {
    float bj[4];
#pragma unroll
    for (int j = 0; j < 4; ++j) bj[j] = bias[col0 + wn * 64 + j * 16 + lcol];
#pragma unroll
    for (int i = 0; i < AI; ++i) {
      int gr0 = row0 + wm * 64 + i * 16 + lrow;
#pragma unroll
      for (int j = 0; j < 4; ++j) {
        int gc = col0 + wn * 64 + j * 16 + lcol;
#pragma unroll
        for (int q = 0; q < 4; ++q) {
          float v = acc[i][j][q] + bj[j];
          size_t off = (size_t)(gr0 + q) * N + gc;
          if constexpr (EPI == 0) {
            ((unsigned short*)Cv)[off] = f2bf(v);
          } else if constexpr (EPI == 1) {
            ((unsigned short*)Cv)[off] = f2bf(v * sigm(v));
          } else {
            ((unsigned short*)Cv)[off] = f2bf(bf2f(R[off]) + alpha * v);
          }
        }
      }
    }
  }
}

// ---------------------------------------------------------------- MFMA windowed attention
__global__ __launch_bounds__(256) void attn_kernel(const unsigned short* __restrict__ QKV,
                                                   unsigned short* __restrict__ O)
{
  __shared__ __align__(16) unsigned short Ks[128 * 64];
  __shared__ __align__(16) unsigned short Vt[64 * 128];
  __shared__ __align__(16) unsigned short Ps[64 * 128];
  int qt = blockIdx.x, h = blockIdx.y, b = blockIdx.z;
  int t = threadIdx.x;
  int l = t & 63, w = t >> 6;
  int q0 = qt * 64;
  int jbase = q0 - 32;

#pragma unroll
  for (int i = 0; i < 4; ++i) {
    int c = t + i * 256;
    int row = c >> 3, sl = c & 7;
    int jg = jbase + row;
    short8 kv = {};
    if ((unsigned)jg < (unsigned)T_)
      kv = *(const short8*)(QKV + ((size_t)(b * T_ + jg)) * 1536 + 512 + h * DH_ + sl * 8);
    *(short8*)(Ks + row * 64 + SW8(row, sl) * 8) = kv;
  }
#pragma unroll
  for (int i = 0; i < 4; ++i) {
    int c = t + i * 256;
    int row = c >> 3, d0 = (c & 7) * 8;
    int jg = jbase + row;
    short8 vv = {};
    if ((unsigned)jg < (unsigned)T_)
      vv = *(const short8*)(QKV + ((size_t)(b * T_ + jg)) * 1536 + 1024 + h * DH_ + d0);
#pragma unroll
    for (int q = 0; q < 8; ++q) {
      int d = d0 + q;
      Vt[d * 128 + SW8(d, row >> 3) * 8 + (row & 7)] = (unsigned short)vv[q];
    }
  }
  short8 qf[2];
#pragma unroll
  for (int ks = 0; ks < 2; ++ks)
    qf[ks] = *(const short8*)(QKV + ((size_t)(b * T_ + q0 + w * 16 + (l & 15))) * 1536
                              + h * DH_ + ks * 32 + (l >> 4) * 8);
  __syncthreads();

  f32x4 sacc[8] = {};
  __builtin_amdgcn_s_setprio(1);
#pragma unroll
  for (int jt = 0; jt < 8; ++jt) {
#pragma unroll
    for (int ks = 0; ks < 2; ++ks) {
      int row = jt * 16 + (l & 15);
      int sl = ks * 4 + (l >> 4);
      short8 kf = *(const short8*)(Ks + row * 64 + SW8(row, sl) * 8);
      sacc[jt] = __builtin_amdgcn_mfma_f32_16x16x32_bf16(qf[ks], kf, sacc[jt], 0, 0, 0);
    }
  }
  __builtin_amdgcn_s_setprio(0);

  const float scale = 0.125f;
  int qgl0 = q0 + w * 16 + ((l >> 4) << 2);
  int jl = jbase + (l & 15);
  float m4[4] = {-3.0e38f, -3.0e38f, -3.0e38f, -3.0e38f};
#pragma unroll
  for (int jt = 0; jt < 8; ++jt) {
#pragma unroll
    for (int r = 0; r < 4; ++r) {
      float s = sacc[jt][r] * scale;
      int jg = jl + jt * 16;
      int dd = jg - (qgl0 + r);
      bool ok = ((unsigned)jg < (unsigned)T_) && (dd <= 32) && (dd >= -32);
      s = ok ? s : -3.0e38f;
      sacc[jt][r] = s;
      m4[r] = fmaxf(m4[r], s);
    }
  }
#pragma unroll
  for (int r = 0; r < 4; ++r) {
    m4[r] = fmaxf(m4[r], __shfl_xor(m4[r], 1, 64));
    m4[r] = fmaxf(m4[r], __shfl_xor(m4[r], 2, 64));
    m4[r] = fmaxf(m4[r], __shfl_xor(m4[r], 4, 64));
    m4[r] = fmaxf(m4[r], __shfl_xor(m4[r], 8, 64));
  }
  float sum4[4] = {0.f, 0.f, 0.f, 0.f};
#pragma unroll
  for (int jt = 0; jt < 8; ++jt) {
#pragma unroll
    for (int r = 0; r < 4; ++r) {
      float e = __expf(sacc[jt][r] - m4[r]);
      sum4[r] += e;
      int qrow = w * 16 + ((l >> 4) << 2) + r;
      int j = jt * 16 + (l & 15);
      Ps[qrow * 128 + SW8(qrow, j >> 3) * 8 + (j & 7)] = f2bf(e);
    }
  }
#pragma unroll
  for (int r = 0; r < 4; ++r) {
    sum4[r] += __shfl_xor(sum4[r], 1, 64);
    sum4[r] += __shfl_xor(sum4[r], 2, 64);
    sum4[r] += __shfl_xor(sum4[r], 4, 64);
    sum4[r] += __shfl_xor(sum4[r], 8, 64);
    sum4[r] = __builtin_amdgcn_rcpf(sum4[r]);
  }

  f32x4 oacc[4] = {};
  __builtin_amdgcn_s_setprio(1);
#pragma unroll
  for (int ks = 0; ks < 4; ++ks) {
    int prow = w * 16 + (l & 15);
    int sl = ks * 4 + (l >> 4);
    short8 pf = *(const short8*)(Ps + prow * 128 + SW8(prow, sl) * 8);
#pragma unroll
    for (int dt = 0; dt < 4; ++dt) {
      int vrow = dt * 16 + (l & 15);
      short8 vf = *(const short8*)(Vt + vrow * 128 + SW8(vrow, sl) * 8);
      oacc[dt] = __builtin_amdgcn_mfma_f32_16x16x32_bf16(pf, vf, oacc[dt], 0, 0, 0);
    }
  }
  __builtin_amdgcn_s_setprio(0);
#pragma unroll
  for (int dt = 0; dt < 4; ++dt) {
#pragma unroll
    for (int r = 0; r < 4; ++r) {
      int qg = q0 + w * 16 + ((l >> 4) << 2) + r;
      int d = dt * 16 + (l & 15);
      O[((size_t)(b * T_ + qg)) * D_ + h * DH_ + d] = f2bf(oacc[dt][r] * sum4[r]);
    }
  }
}

// ---------------------------------------------------------------- depthwise conv k=31, 2 channels/thread, + GN partials
#define TT_ 16
__global__ __launch_bounds__(256) void dwconv_kernel(const unsigned short* __restrict__ X,
    const float* __restrict__ w, const float* __restrict__ bias,
    unsigned short* __restrict__ Y, float* __restrict__ red)
{
  int t = threadIdx.x;
  int gid = blockIdx.x;              // B * (T/16) * (EC/512) = 1024
  int ecb = gid & 1;
  int tt  = (gid >> 1) & 63;
  int b   = gid >> 7;
  int e0 = ecb * 512 + t * 2;
  int t0 = tt * TT_;
  const unsigned short* xp = X + (size_t)b * T_ * EC_ + e0;

  float wr0[KW_], wr1[KW_];
#pragma unroll
  for (int k = 0; k < KW_; ++k) { wr0[k] = w[e0 * KW_ + k]; wr1[k] = w[(e0 + 1) * KW_ + k]; }
  float out0[TT_], out1[TT_];
  float bv0 = bias[e0], bv1 = bias[e0 + 1];
#pragma unroll
  for (int i = 0; i < TT_; ++i) { out0[i] = bv0; out1[i] = bv1; }

#pragma unroll
  for (int j = 0; j < TT_ + KW_ - 1; ++j) {
    int tj = t0 - 15 + j;
    float x0 = 0.f, x1 = 0.f;
    if ((unsigned)tj < (unsigned)T_) {
      ushort2v u = *(const ushort2v*)(xp + (size_t)tj * EC_);
      x0 = bf2f(u.x); x1 = bf2f(u.y);
    }
#pragma unroll
    for (int i = 0; i < TT_; ++i) {
      int k = j - i;
      if (k >= 0 && k < KW_) {
        out0[i] = fmaf(x0, wr0[k], out0[i]);
        out1[i] = fmaf(x1, wr1[k], out1[i]);
      }
    }
  }
  unsigned short* yp = Y + ((size_t)b * T_ + t0) * EC_ + e0;
  float s = 0.f, s2 = 0.f;
#pragma unroll
  for (int i = 0; i < TT_; ++i) {
    ushort2v o; o.x = f2bf(out0[i]); o.y = f2bf(out1[i]);
    *(ushort2v*)(yp + (size_t)i * EC_) = o;
    s += out0[i] + out1[i];
    s2 += out0[i] * out0[i] + out1[i] * out1[i];
  }
#pragma unroll
  for (int off = 32; off; off >>= 1) {
    s  += __shfl_down(s,  off, 64);
    s2 += __shfl_down(s2, off, 64);
  }
  __shared__ float rs[4], rq[4];
  if ((t & 63) == 0) { rs[t >> 6] = s; rq[t >> 6] = s2; }
  __syncthreads();
  if (t == 0) {
    int loc = gid & 127;
    red[(b * 128 + loc) * 2]     = rs[0] + rs[1] + rs[2] + rs[3];
    red[(b * 128 + loc) * 2 + 1] = rq[0] + rq[1] + rq[2] + rq[3];
  }
}

// ---------------------------------------------------------------- GN stats (128 partials/sample)
__global__ __launch_bounds__(256) void gn_stats_kernel(const float* __restrict__ partial,
                                                       float* __restrict__ stats)
{
  int b = blockIdx.x, t = threadIdx.x;
  float s = 0.f, s2 = 0.f;
  if (t < 128) {
    s  = partial[b * 256 + t * 2];
    s2 = partial[b * 256 + t * 2 + 1];
  }
#pragma unroll
  for (int off = 32; off; off >>= 1) {
    s  += __shfl_down(s,  off, 64);
    s2 += __shfl_down(s2, off, 64);
  }
  __shared__ float rs[4], rq[4];
  if ((t & 63) == 0) { rs[t >> 6] = s; rq[t >> 6] = s2; }
  __syncthreads();
  if (t == 0) {
    float S = rs[0] + rs[1] + rs[2] + rs[3];
    float S2 = rq[0] + rq[1] + rq[2] + rq[3];
    const float n = (float)(T_ * EC_);
    float mean = S / n;
    float var  = S2 / n - mean * mean;
    stats[b * 2]     = mean;
    stats[b * 2 + 1] = __builtin_amdgcn_rsqf(var + 1e-5f);
  }
}

// reads bf16 conv-out, writes silu(gn(..)) bf16 -- 8 elems/thread
__global__ __launch_bounds__(256) void gn_apply_kernel(const unsigned short* __restrict__ X,
    const float* __restrict__ stats, const float* __restrict__ g, const float* __restrict__ bb,
    unsigned short* __restrict__ out)
{
  int idx = blockIdx.x * 256 + threadIdx.x;   // 8-elem chunk index over [B,T,EC]
  int e8 = (idx & 127) << 3;
  int bt = idx >> 7;
  int b  = bt >> 10;
  float mean = stats[b * 2], rstd = stats[b * 2 + 1];
  short8 v = *(const short8*)(X + (size_t)idx * 8);
  float4 g0 = *(const float4*)(g + e8);
  float4 g1 = *(const float4*)(g + e8 + 4);
  float4 b0 = *(const float4*)(bb + e8);
  float4 b1 = *(const float4*)(bb + e8 + 4);
  float gg[8] = {g0.x, g0.y, g0.z, g0.w, g1.x, g1.y, g1.z, g1.w};
  float bv[8] = {b0.x, b0.y, b0.z, b0.w, b1.x, b1.y, b1.z, b1.w};
  short8 o;
#pragma unroll
  for (int j = 0; j < 8; ++j) {
    float u = (bf2f((unsigned short)v[j]) - mean) * rstd * gg[j] + bv[j];
    o[j] = (short)f2bf(u * sigm(u));
  }
  *(short8*)(out + (size_t)idx * 8) = o;
}

// ---------------------------------------------------------------- launch
extern "C" void kernel_launch(void* const* d_in, const int* in_sizes, int n_in,
                              void* d_out, int out_size, void* d_ws, size_t ws_size,
                              hipStream_t stream)
{
  const float* in_x      = (const float*)d_in[0];
  const float* ffn1_ln_g = (const float*)d_in[1];
  const float* ffn1_ln_b = (const float*)d_in[2];
  const float* ffn1_w1   = (const float*)d_in[3];
  const float* ffn1_b1   = (const float*)d_in[4];
  const float* ffn1_w2   = (const float*)d_in[5];
  const float* ffn1_b2   = (const float*)d_in[6];
  const float* attn_ln_g = (const float*)d_in[7];
  const float* attn_ln_b = (const float*)d_in[8];
  const float* qkv_w     = (const float*)d_in[9];
  const float* qkv_b     = (const float*)d_in[10];
  const float* outp_w    = (const float*)d_in[11];
  const float* outp_b    = (const float*)d_in[12];
  const float* conv_ln_g = (const float*)d_in[13];
  const float* conv_ln_b = (const float*)d_in[14];
  const float* pw1_w     = (const float*)d_in[15];
  const float* pw1_b     = (const float*)d_in[16];
  const float* dw_w      = (const float*)d_in[17];
  const float* dw_b      = (const float*)d_in[18];
  const float* gn_g      = (const float*)d_in[19];
  const float* gn_b      = (const float*)d_in[20];
  const float* pw2_w     = (const float*)d_in[21];
  const float* pw2_b     = (const float*)d_in[22];
  const float* ffn2_ln_g = (const float*)d_in[23];
  const float* ffn2_ln_b = (const float*)d_in[24];
  const float* ffn2_w1   = (const float*)d_in[25];
  const float* ffn2_b1   = (const float*)d_in[26];
  const float* ffn2_w2   = (const float*)d_in[27];
  const float* ffn2_b2   = (const float*)d_in[28];
  const float* blk_ln_g  = (const float*)d_in[29];
  const float* blk_ln_b  = (const float*)d_in[30];
  const float* fin_ln_g  = (const float*)d_in[31];
  const float* fin_ln_b  = (const float*)d_in[32];

  char* p = (char*)d_ws;
  unsigned short* x    = (unsigned short*)p; p += (size_t)ROWS * D_ * 2;   // bf16 residual
  unsigned short* big3 = (unsigned short*)p; p += (size_t)ROWS * EC_ * 2;  // conv out bf16
  float* red  = (float*)p;          p += 8192 * 4;
  unsigned short* abuf  = (unsigned short*)p; p += (size_t)ROWS * D_ * 2;
  unsigned short* inner = (unsigned short*)p; p += (size_t)ROWS * FF_ * 2;
  unsigned short* big2  = (unsigned short*)p; p += (size_t)ROWS * EC_ * 2;
  unsigned short* wt_w1a = (unsigned short*)p; p += (size_t)L_ * D_ * FF_ * 2;
  unsigned short* wt_w1b = (unsigned short*)p; p += (size_t)L_ * FF_ * D_ * 2;
  unsigned short* wt_qkv = (unsigned short*)p; p += (size_t)L_ * D_ * 1536 * 2;
  unsigned short* wt_out = (unsigned short*)p; p += (size_t)L_ * D_ * D_ * 2;
  unsigned short* wt_pw1 = (unsigned short*)p; p += (size_t)L_ * D_ * 2048 * 2;
  unsigned short* wt_pw2 = (unsigned short*)p; p += (size_t)L_ * EC_ * D_ * 2;
  unsigned short* wt_w2a = (unsigned short*)p; p += (size_t)L_ * D_ * FF_ * 2;
  unsigned short* wt_w2b = (unsigned short*)p; p += (size_t)L_ * FF_ * D_ * 2;
  float* stats = red + 4096;

  dim3 blk256(256);
  // fused initial convert + first FFN1 LN
  cvt_ln_kernel<<<ROWS/4, blk256, 0, stream>>>(in_x, ffn1_ln_g, ffn1_ln_b, x, abuf);

  wtr_kernel<<<dim3(FF_/32,  D_/32,  L_), blk256, 0, stream>>>(ffn1_w1, wt_w1a, D_, FF_);
  wtr_kernel<<<dim3(D_/32,   FF_/32, L_), blk256, 0, stream>>>(ffn1_w2, wt_w1b, FF_, D_);
  wtr_kernel<<<dim3(1536/32, D_/32,  L_), blk256, 0, stream>>>(qkv_w,   wt_qkv, D_, 1536);
  wtr_kernel<<<dim3(D_/32,   D_/32,  L_), blk256, 0, stream>>>(outp_w,  wt_out, D_, D_);
  wtr_kernel<<<dim3(2048/32, D_/32,  L_), blk256, 0, stream>>>(pw1_w,   wt_pw1, D_, 2048);
  wtr_kernel<<<dim3(D_/32,   EC_/32, L_), blk256, 0, stream>>>(pw2_w,   wt_pw2, EC_, D_);
  wtr_kernel<<<dim3(FF_/32,  D_/32,  L_), blk256, 0, stream>>>(ffn2_w1, wt_w2a, D_, FF_);
  wtr_kernel<<<dim3(D_/32,   FF_/32, L_), blk256, 0, stream>>>(ffn2_w2, wt_w2b, FF_, D_);

  for (int l = 0; l < L_; ++l) {
    // ---- FFN1 ----
    gemm_mfma<1><<<dim3(FF_/128, ROWS/128), blk256, 0, stream>>>(
        abuf, wt_w1a + (size_t)l*D_*FF_, ffn1_b1 + l*FF_, nullptr, inner, FF_, D_, 0.f);
    gemm_mfma<2><<<dim3(D_/128, ROWS/128), blk256, 0, stream>>>(
        inner, wt_w1b + (size_t)l*FF_*D_, ffn1_b2 + l*D_, x, x, D_, FF_, 0.5f);

    // ---- local windowed MHSA ----
    ln_bf16_kernel<<<ROWS/4, blk256, 0, stream>>>(x, attn_ln_g + l*D_, attn_ln_b + l*D_, abuf);
    gemm_mfma<0><<<dim3(1536/128, ROWS/128), blk256, 0, stream>>>(
        abuf, wt_qkv + (size_t)l*D_*1536, qkv_b + l*1536, nullptr, inner, 1536, D_, 0.f);
    attn_kernel<<<dim3(T_/64, H_, B_), blk256, 0, stream>>>(inner, abuf);
    gemm_mfma<2><<<dim3(D_/128, ROWS/128), blk256, 0, stream>>>(
        abuf, wt_out + (size_t)l*D_*D_, outp_b + l*D_, x, x, D_, D_, 1.0f);

    // ---- conv module (pw1 + GLU fused) ----
    ln_bf16_kernel<<<ROWS/4, blk256, 0, stream>>>(x, conv_ln_g + l*D_, conv_ln_b + l*D_, abuf);
    gemm_mfma<3><<<dim3(EC_/64, ROWS/128), blk256, 0, stream>>>(
        abuf, wt_pw1 + (size_t)l*D_*2048, pw1_b + l*2048, nullptr, big2, EC_, D_, 0.f);
    dwconv_kernel<<<B_ * (T_/TT_) * (EC_/512), blk256, 0, stream>>>(
        big2, dw_w + (size_t)l*EC_*KW_, dw_b + l*EC_, big3, red);
    gn_stats_kernel<<<B_, blk256, 0, stream>>>(red, stats);
    gn_apply_kernel<<<(ROWS * EC_ / 8) / 256, blk256, 0, stream>>>(
        big3, stats, gn_g + l*EC_, gn_b + l*EC_, big2);
    gemm_mfma<2><<<dim3(D_/128, ROWS/128), blk256, 0, stream>>>(
        big2, wt_pw2 + (size_t)l*EC_*D_, pw2_b + l*D_, x, x, D_, EC_, 1.0f);

    // ---- FFN2 ----
    ln_bf16_kernel<<<ROWS/4, blk256, 0, stream>>>(x, ffn2_ln_g + l*D_, ffn2_ln_b + l*D_, abuf);
    gemm_mfma<1><<<dim3(FF_/128, ROWS/128), blk256, 0, stream>>>(
        abuf, wt_w2a + (size_t)l*D_*FF_, ffn2_b1 + l*FF_, nullptr, inner, FF_, D_, 0.f);
    gemm_mfma<2><<<dim3(D_/128, ROWS/128), blk256, 0, stream>>>(
        inner, wt_w2b + (size_t)l*FF_*D_, ffn2_b2 + l*D_, x, x, D_, FF_, 0.5f);

    // ---- boundary: blk LN fused with next LN ----
    if (l < L_ - 1) {
      ln_dual_kernel<true><<<ROWS/4, blk256, 0, stream>>>(
          x, blk_ln_g + l*D_, blk_ln_b + l*D_,
          ffn1_ln_g + (l+1)*D_, ffn1_ln_b + (l+1)*D_, x, abuf);
    } else {
      ln_dual_kernel<false><<<ROWS/4, blk256, 0, stream>>>(
          x, blk_ln_g + l*D_, blk_ln_b + l*D_, fin_ln_g, fin_ln_b, x, d_out);
    }
  }
}

// Round 19
// 1102.175 us; speedup vs baseline: 1.0626x; 1.0626x over previous
//
#include <hip/hip_runtime.h>
#include <hip/hip_bf16.h>
#include <math.h>

#define L_ 4
#define D_ 512
#define H_ 8
#define T_ 1024
#define B_ 8
#define FF_ 2048
#define EC_ 1024
#define KW_ 31
#define DH_ 64
#define ROWS (B_*T_)   // 8192

typedef __attribute__((ext_vector_type(8))) short short8;
typedef __attribute__((ext_vector_type(4))) float f32x4;
typedef __attribute__((ext_vector_type(4))) unsigned short ushort4v;
typedef __attribute__((ext_vector_type(2))) unsigned short ushort2v;

static __device__ __forceinline__ unsigned short f2bf(float f) {
  __hip_bfloat16 h = __float2bfloat16(f);   // native RNE cvt
  unsigned short u;
  __builtin_memcpy(&u, &h, 2);
  return u;
}
static __device__ __forceinline__ float bf2f(unsigned short h) {
  union { unsigned u; float f; } v; v.u = ((unsigned)h) << 16;
  return v.f;
}
static __device__ __forceinline__ float sigm(float x) {
  return __builtin_amdgcn_rcpf(1.0f + __expf(-x));
}

#define GLDS(gp, lp) __builtin_amdgcn_global_load_lds( \
    (const __attribute__((address_space(1))) unsigned int*)(const void*)(gp), \
    (__attribute__((address_space(3))) unsigned int*)(void*)(lp), 16, 0, 0)

// 8-slot-per-row XOR swizzle (rows of 8x16B)
#define SW8(row, slot) ((slot) ^ (((row) ^ ((row) >> 3)) & 7))

// ---------------------------------------------------------------- fused f32->bf16 convert + LayerNorm
__global__ __launch_bounds__(256) void cvt_ln_kernel(const float* __restrict__ in,
    const float* __restrict__ g, const float* __restrict__ b,
    unsigned short* __restrict__ x, unsigned short* __restrict__ y)
{
  int row = blockIdx.x * 4 + (threadIdx.x >> 6);
  int l = threadIdx.x & 63;
  const float* ir = in + (size_t)row * D_ + l * 8;
  float4 v0 = *(const float4*)ir;
  float4 v1 = *(const float4*)(ir + 4);
  float raw[8] = {v0.x, v0.y, v0.z, v0.w, v1.x, v1.y, v1.z, v1.w};
  short8 xo;
  float vv[8];
#pragma unroll
  for (int j = 0; j < 8; ++j) {
    unsigned short h = f2bf(raw[j]);
    xo[j] = (short)h;
    vv[j] = bf2f(h);
  }
  *(short8*)(x + (size_t)row * D_ + l * 8) = xo;
  float s = 0.f, s2 = 0.f;
#pragma unroll
  for (int j = 0; j < 8; ++j) { s += vv[j]; s2 += vv[j] * vv[j]; }
#pragma unroll
  for (int off = 32; off; off >>= 1) {
    s  += __shfl_xor(s,  off, 64);
    s2 += __shfl_xor(s2, off, 64);
  }
  float mean = s * (1.0f / D_);
  float var  = s2 * (1.0f / D_) - mean * mean;
  float r = __builtin_amdgcn_rsqf(var + 1e-5f);
  float4 g0 = *(const float4*)(g + l * 8);
  float4 g1 = *(const float4*)(g + l * 8 + 4);
  float4 b0 = *(const float4*)(b + l * 8);
  float4 b1 = *(const float4*)(b + l * 8 + 4);
  float gg[8] = {g0.x, g0.y, g0.z, g0.w, g1.x, g1.y, g1.z, g1.w};
  float bb[8] = {b0.x, b0.y, b0.z, b0.w, b1.x, b1.y, b1.z, b1.w};
  short8 o;
#pragma unroll
  for (int j = 0; j < 8; ++j) o[j] = (short)f2bf((vv[j] - mean) * r * gg[j] + bb[j]);
  *(short8*)(y + (size_t)row * D_ + l * 8) = o;
}

// ---------------------------------------------------------------- LayerNorm (bf16 in, bf16 out), wave/row
__global__ __launch_bounds__(256) void ln_bf16_kernel(const unsigned short* __restrict__ x,
    const float* __restrict__ g, const float* __restrict__ b, unsigned short* __restrict__ y)
{
  int row = blockIdx.x * 4 + (threadIdx.x >> 6);
  int l = threadIdx.x & 63;
  short8 xr = *(const short8*)(x + (size_t)row * D_ + l * 8);
  float vv[8];
#pragma unroll
  for (int j = 0; j < 8; ++j) vv[j] = bf2f((unsigned short)xr[j]);
  float s = 0.f, s2 = 0.f;
#pragma unroll
  for (int j = 0; j < 8; ++j) { s += vv[j]; s2 += vv[j] * vv[j]; }
#pragma unroll
  for (int off = 32; off; off >>= 1) {
    s  += __shfl_xor(s,  off, 64);
    s2 += __shfl_xor(s2, off, 64);
  }
  float mean = s * (1.0f / D_);
  float var  = s2 * (1.0f / D_) - mean * mean;
  float r = __builtin_amdgcn_rsqf(var + 1e-5f);
  float4 g0 = *(const float4*)(g + l * 8);
  float4 g1 = *(const float4*)(g + l * 8 + 4);
  float4 b0 = *(const float4*)(b + l * 8);
  float4 b1 = *(const float4*)(b + l * 8 + 4);
  float gg[8] = {g0.x, g0.y, g0.z, g0.w, g1.x, g1.y, g1.z, g1.w};
  float bb[8] = {b0.x, b0.y, b0.z, b0.w, b1.x, b1.y, b1.z, b1.w};
  short8 o;
#pragma unroll
  for (int j = 0; j < 8; ++j) o[j] = (short)f2bf((vv[j] - mean) * r * gg[j] + bb[j]);
  *(short8*)(y + (size_t)row * D_ + l * 8) = o;
}

// ---------------------------------------------------------------- dual LayerNorm (bf16 x)
template<bool BF2>
__global__ __launch_bounds__(256) void ln_dual_kernel(const unsigned short* __restrict__ x,
    const float* __restrict__ g1, const float* __restrict__ b1,
    const float* __restrict__ g2, const float* __restrict__ b2,
    unsigned short* __restrict__ y1, void* __restrict__ y2)
{
  int row = blockIdx.x * 4 + (threadIdx.x >> 6);
  int l = threadIdx.x & 63;
  short8 xr = *(const short8*)(x + (size_t)row * D_ + l * 8);
  float vv[8];
#pragma unroll
  for (int j = 0; j < 8; ++j) vv[j] = bf2f((unsigned short)xr[j]);
  float s = 0.f, s2 = 0.f;
#pragma unroll
  for (int j = 0; j < 8; ++j) { s += vv[j]; s2 += vv[j] * vv[j]; }
#pragma unroll
  for (int off = 32; off; off >>= 1) {
    s  += __shfl_xor(s,  off, 64);
    s2 += __shfl_xor(s2, off, 64);
  }
  float mean = s * (1.0f / D_);
  float var  = s2 * (1.0f / D_) - mean * mean;
  float r = __builtin_amdgcn_rsqf(var + 1e-5f);
  float4 g0 = *(const float4*)(g1 + l * 8);
  float4 g1v = *(const float4*)(g1 + l * 8 + 4);
  float4 b0 = *(const float4*)(b1 + l * 8);
  float4 b1v = *(const float4*)(b1 + l * 8 + 4);
  float ga[8] = {g0.x, g0.y, g0.z, g0.w, g1v.x, g1v.y, g1v.z, g1v.w};
  float ba[8] = {b0.x, b0.y, b0.z, b0.w, b1v.x, b1v.y, b1v.z, b1v.w};
  float yv[8];
  float u = 0.f, u2 = 0.f;
#pragma unroll
  for (int j = 0; j < 8; ++j) {
    yv[j] = (vv[j] - mean) * r * ga[j] + ba[j];
    u += yv[j]; u2 += yv[j] * yv[j];
  }
  {
    short8 o;
#pragma unroll
    for (int j = 0; j < 8; ++j) o[j] = (short)f2bf(yv[j]);
    *(short8*)(y1 + (size_t)row * D_ + l * 8) = o;
  }
#pragma unroll
  for (int off = 32; off; off >>= 1) {
    u  += __shfl_xor(u,  off, 64);
    u2 += __shfl_xor(u2, off, 64);
  }
  float mean2 = u * (1.0f / D_);
  float var2  = u2 * (1.0f / D_) - mean2 * mean2;
  float r2 = __builtin_amdgcn_rsqf(var2 + 1e-5f);
  float4 c0 = *(const float4*)(g2 + l * 8);
  float4 c1 = *(const float4*)(g2 + l * 8 + 4);
  float4 d0 = *(const float4*)(b2 + l * 8);
  float4 d1 = *(const float4*)(b2 + l * 8 + 4);
  float gc[8] = {c0.x, c0.y, c0.z, c0.w, c1.x, c1.y, c1.z, c1.w};
  float bc[8] = {d0.x, d0.y, d0.z, d0.w, d1.x, d1.y, d1.z, d1.w};
  if constexpr (BF2) {
    short8 o;
#pragma unroll
    for (int j = 0; j < 8; ++j) o[j] = (short)f2bf((yv[j] - mean2) * r2 * gc[j] + bc[j]);
    *(short8*)((unsigned short*)y2 + (size_t)row * D_ + l * 8) = o;
  } else {
    float z[8];
#pragma unroll
    for (int j = 0; j < 8; ++j) z[j] = (yv[j] - mean2) * r2 * gc[j] + bc[j];
    float4 o0 = {z[0], z[1], z[2], z[3]};
    float4 o1 = {z[4], z[5], z[6], z[7]};
    float* yp = (float*)y2 + (size_t)row * D_ + l * 8;
    *(float4*)yp = o0; *(float4*)(yp + 4) = o1;
  }
}

// ---------------------------------------------------------------- weight fp32[K][N] -> bf16[N][K]
__global__ __launch_bounds__(256) void wtr_kernel(const float* __restrict__ W,
    unsigned short* __restrict__ Wt, int K, int N)
{
  __shared__ float tile[32][33];
  const float* Wl = W + (size_t)blockIdx.z * K * N;
  unsigned short* Wtl = Wt + (size_t)blockIdx.z * K * N;
  int n0 = blockIdx.x * 32, k0 = blockIdx.y * 32;
  int c = threadIdx.x & 31, r = threadIdx.x >> 5;
#pragma unroll
  for (int it = 0; it < 4; ++it) {
    int kk = r + it * 8;
    tile[kk][c] = Wl[(size_t)(k0 + kk) * N + n0 + c];
  }
  __syncthreads();
#pragma unroll
  for (int it = 0; it < 4; ++it) {
    int nn = r + it * 8;
    Wtl[(size_t)(n0 + nn) * K + k0 + c] = f2bf(tile[c][nn]);
  }
}

// ---------------------------------------------------------------- bf16 MFMA GEMM (wide, TM=128, BK=64)
// ring-2 LDS (64 KB), two-barrier iteration, 8 GLDS/tile/thread, XCD swizzle.
template<int EPI>
__global__ __launch_bounds__(256) void gemm_mfma(
    const unsigned short* __restrict__ A, const unsigned short* __restrict__ Wt,
    const float* __restrict__ bias, void* __restrict__ Cv,
    int N, int K)
{
  constexpr int AI = 4;
  __shared__ __align__(16) unsigned short As[2][128 * 64];   // 32 KB
  __shared__ __align__(16) unsigned short Bs[2][128 * 64];   // 32 KB
  int t = threadIdx.x;
  int gx = gridDim.x;
  int nwg = gx * gridDim.y;
  int orig = blockIdx.y * gx + blockIdx.x;
  int lg = (orig & 7) * (nwg >> 3) + (orig >> 3);
  int row0 = (lg / gx) * 128;
  int col0 = (lg % gx) * (EPI == 3 ? 64 : 128);
  int l = t & 63, w = t >> 6, wm = w >> 1, wn = w & 1;

  const unsigned short* agp[4];
  const unsigned short* bgp[4];
#pragma unroll
  for (int q = 0; q < 4; ++q) {
    int c = t + q * 256;
    int row = c >> 3, s = (c & 7) ^ (row & 7);
    agp[q] = A + (size_t)(row0 + row) * K + s * 8;
    int brow;
    if constexpr (EPI == 3)
      brow = (row < 64) ? (col0 + row) : (EC_ + col0 + (row - 64));
    else
      brow = col0 + row;
    bgp[q] = Wt + (size_t)brow * K + s * 8;
  }

  int lcol = l & 15, kq = l >> 4, lrow = kq * 4;
  int aoff[AI][2], boff[4][2];
#pragma unroll
  for (int i = 0; i < AI; ++i) {
    int row = wm * 64 + i * 16 + lcol;
#pragma unroll
    for (int kk = 0; kk < 2; ++kk)
      aoff[i][kk] = row * 64 + (((kk * 4 + kq) ^ (row & 7)) * 8);
  }
#pragma unroll
  for (int j = 0; j < 4; ++j) {
    int row;
    if constexpr (EPI == 3)
      row = (j < 2 ? wn * 32 + j * 16 : 64 + wn * 32 + (j - 2) * 16) + lcol;
    else
      row = wn * 64 + j * 16 + lcol;
#pragma unroll
    for (int kk = 0; kk < 2; ++kk)
      boff[j][kk] = row * 64 + (((kk * 4 + kq) ^ (row & 7)) * 8);
  }

  f32x4 acc[AI][4] = {};
  int nt = K >> 6;

  auto stage = [&](int buf) {
#pragma unroll
    for (int q = 0; q < 4; ++q) {
      GLDS(agp[q], As[buf] + (t + q * 256) * 8);
      GLDS(bgp[q], Bs[buf] + (t + q * 256) * 8);
      agp[q] += 64; bgp[q] += 64;
    }
  };
  stage(0); stage(1);

  for (int kt = 0; kt < nt; ++kt) {
    int cur = kt & 1;
    if (kt < nt - 1) asm volatile("s_waitcnt vmcnt(8)" ::: "memory");
    else             asm volatile("s_waitcnt vmcnt(0)" ::: "memory");
    __builtin_amdgcn_s_barrier();
    __builtin_amdgcn_sched_barrier(0);
    const unsigned short* Ab = As[cur];
    const unsigned short* Bb = Bs[cur];
    short8 af[AI][2], bfr[4][2];
#pragma unroll
    for (int i = 0; i < AI; ++i)
#pragma unroll
      for (int kk = 0; kk < 2; ++kk) af[i][kk] = *(const short8*)(Ab + aoff[i][kk]);
#pragma unroll
    for (int j = 0; j < 4; ++j)
#pragma unroll
      for (int kk = 0; kk < 2; ++kk) bfr[j][kk] = *(const short8*)(Bb + boff[j][kk]);
    __builtin_amdgcn_s_setprio(1);
#pragma unroll
    for (int kk = 0; kk < 2; ++kk)
#pragma unroll
      for (int i = 0; i < AI; ++i)
#pragma unroll
        for (int j = 0; j < 4; ++j)
          acc[i][j] = __builtin_amdgcn_mfma_f32_16x16x32_bf16(af[i][kk], bfr[j][kk],
                                                              acc[i][j], 0, 0, 0);
    __builtin_amdgcn_s_setprio(0);
    __builtin_amdgcn_s_barrier();
    __builtin_amdgcn_sched_barrier(0);
    if (kt + 2 < nt) stage(cur);
  }

  if constexpr (EPI == 3) {
    float bja[2], bjg[2];
#pragma unroll
    for (int j = 0; j < 2; ++j) {
      int c = col0 + wn * 32 + j * 16 + lcol;
      bja[j] = bias[c];
      bjg[j] = bias[EC_ + c];
    }
#pragma unroll
    for (int i = 0; i < AI; ++i) {
      int gr0 = row0 + wm * 64 + i * 16 + lrow;
#pragma unroll
      for (int j = 0; j < 2; ++j) {
        int gc = col0 + wn * 32 + j * 16 + lcol;
#pragma unroll
        for (int q = 0; q < 4; ++q) {
          float a = acc[i][j][q] + bja[j];
          float g = acc[i][j + 2][q] + bjg[j];
          ((unsigned short*)Cv)[(size_t)(gr0 + q) * N + gc] = f2bf(a * sigm(g));
        }
      }
    }
  } else {
    float bj[4];
#pragma unroll
    for (int j = 0; j < 4; ++j) bj[j] = bias[col0 + wn * 64 + j * 16 + lcol];
#pragma unroll
    for (int i = 0; i < AI; ++i) {
      int gr0 = row0 + wm * 64 + i * 16 + lrow;
#pragma unroll
      for (int j = 0; j < 4; ++j) {
        int gc = col0 + wn * 64 + j * 16 + lcol;
#pragma unroll
        for (int q = 0; q < 4; ++q) {
          float v = acc[i][j][q] + bj[j];
          size_t off = (size_t)(gr0 + q) * N + gc;
          if constexpr (EPI == 0) {
            ((unsigned short*)Cv)[off] = f2bf(v);
          } else {
            ((unsigned short*)Cv)[off] = f2bf(v * sigm(v));
          }
        }
      }
    }
  }
}

// ---------------------------------------------------------------- bf16 MFMA GEMM, residual class
// 64x128 tile, BK=64, 256 thr, ring-2 LDS (48 KB -> 3 blocks/CU), two-barrier iteration.
__global__ __launch_bounds__(256) void gemm_res64(
    const unsigned short* __restrict__ A, const unsigned short* __restrict__ Wt,
    const float* __restrict__ bias, const unsigned short* __restrict__ R,
    unsigned short* __restrict__ C, int N, int K, float alpha)
{
  __shared__ __align__(16) unsigned short As[2][64 * 64];    // 16 KB
  __shared__ __align__(16) unsigned short Bs[2][128 * 64];   // 32 KB
  int t = threadIdx.x;
  int gx = gridDim.x;
  int nwg = gx * gridDim.y;
  int orig = blockIdx.y * gx + blockIdx.x;
  int lg = (orig & 7) * (nwg >> 3) + (orig >> 3);
  int row0 = (lg / gx) * 64;
  int col0 = (lg % gx) * 128;
  int l = t & 63, w = t >> 6, wm = w >> 1, wn = w & 1;

  int arA0 = t >> 3;
  int sA0  = (t & 7) ^ (arA0 & 7);
  int cA1  = t + 256;
  int arA1 = cA1 >> 3;
  int sA1  = (cA1 & 7) ^ (arA1 & 7);
  const unsigned short* agp0 = A + (size_t)(row0 + arA0) * K + sA0 * 8;
  const unsigned short* agp1 = A + (size_t)(row0 + arA1) * K + sA1 * 8;
  const unsigned short* bgp[4];
#pragma unroll
  for (int q = 0; q < 4; ++q) {
    int c = t + q * 256;
    int r = c >> 3, s = (c & 7) ^ (r & 7);
    bgp[q] = Wt + (size_t)(col0 + r) * K + s * 8;
  }

  int lcol = l & 15, kq = l >> 4, lrow = kq * 4;
  int aoff[2][2], boff[4][2];
#pragma unroll
  for (int i = 0; i < 2; ++i) {
    int row = wm * 32 + i * 16 + lcol;
#pragma unroll
    for (int kk = 0; kk < 2; ++kk)
      aoff[i][kk] = row * 64 + (((kk * 4 + kq) ^ (row & 7)) * 8);
  }
#pragma unroll
  for (int j = 0; j < 4; ++j) {
    int row = wn * 64 + j * 16 + lcol;
#pragma unroll
    for (int kk = 0; kk < 2; ++kk)
      boff[j][kk] = row * 64 + (((kk * 4 + kq) ^ (row & 7)) * 8);
  }

  f32x4 acc[2][4] = {};
  int nt = K >> 6;

  auto stage = [&](int buf) {
    GLDS(agp0, As[buf] + t * 8);
    GLDS(agp1, As[buf] + (t + 256) * 8);
#pragma unroll
    for (int q = 0; q < 4; ++q) GLDS(bgp[q], Bs[buf] + (t + q * 256) * 8);
    agp0 += 64; agp1 += 64;
#pragma unroll
    for (int q = 0; q < 4; ++q) bgp[q] += 64;
  };
  stage(0); stage(1);

  for (int kt = 0; kt < nt; ++kt) {
    int cur = kt & 1;
    if (kt < nt - 1) asm volatile("s_waitcnt vmcnt(6)" ::: "memory");
    else             asm volatile("s_waitcnt vmcnt(0)" ::: "memory");
    __builtin_amdgcn_s_barrier();
    __builtin_amdgcn_sched_barrier(0);
    const unsigned short* Ab = As[cur];
    const unsigned short* Bb = Bs[cur];
    short8 af[2][2], bfr[4][2];
#pragma unroll
    for (int i = 0; i < 2; ++i)
#pragma unroll
      for (int kk = 0; kk < 2; ++kk) af[i][kk] = *(const short8*)(Ab + aoff[i][kk]);
#pragma unroll
    for (int j = 0; j < 4; ++j)
#pragma unroll
      for (int kk = 0; kk < 2; ++kk) bfr[j][kk] = *(const short8*)(Bb + boff[j][kk]);
    __builtin_amdgcn_s_setprio(1);
#pragma unroll
    for (int kk = 0; kk < 2; ++kk)
#pragma unroll
      for (int i = 0; i < 2; ++i)
#pragma unroll
        for (int j = 0; j < 4; ++j)
          acc[i][j] = __builtin_amdgcn_mfma_f32_16x16x32_bf16(af[i][kk], bfr[j][kk],
                                                              acc[i][j], 0, 0, 0);
    __builtin_amdgcn_s_setprio(0);
    __builtin_amdgcn_s_barrier();
    __builtin_amdgcn_sched_barrier(0);
    if (kt + 2 < nt) stage(cur);
  }

  float bj[4];
#pragma unroll
  for (int j = 0; j < 4; ++j) bj[j] = bias[col0 + wn * 64 + j * 16 + lcol];
#pragma unroll
  for (int i = 0; i < 2; ++i) {
    int gr0 = row0 + wm * 32 + i * 16 + lrow;
#pragma unroll
    for (int j = 0; j < 4; ++j) {
      int gc = col0 + wn * 64 + j * 16 + lcol;
#pragma unroll
      for (int q = 0; q < 4; ++q) {
        size_t off = (size_t)(gr0 + q) * N + gc;
        C[off] = f2bf(bf2f(R[off]) + alpha * (acc[i][j][q] + bj[j]));
      }
    }
  }
}

// ---------------------------------------------------------------- MFMA windowed attention
__global__ __launch_bounds__(256) void attn_kernel(const unsigned short* __restrict__ QKV,
                                                   unsigned short* __restrict__ O)
{
  __shared__ __align__(16) unsigned short Ks[128 * 64];
  __shared__ __align__(16) unsigned short Vt[64 * 128];
  __shared__ __align__(16) unsigned short Ps[64 * 128];
  int qt = blockIdx.x, h = blockIdx.y, b = blockIdx.z;
  int t = threadIdx.x;
  int l = t & 63, w = t >> 6;
  int q0 = qt * 64;
  int jbase = q0 - 32;

#pragma unroll
  for (int i = 0; i < 4; ++i) {
    int c = t + i * 256;
    int row = c >> 3, sl = c & 7;
    int jg = jbase + row;
    short8 kv = {};
    if ((unsigned)jg < (unsigned)T_)
      kv = *(const short8*)(QKV + ((size_t)(b * T_ + jg)) * 1536 + 512 + h * DH_ + sl * 8);
    *(short8*)(Ks + row * 64 + SW8(row, sl) * 8) = kv;
  }
#pragma unroll
  for (int i = 0; i < 4; ++i) {
    int c = t + i * 256;
    int row = c >> 3, d0 = (c & 7) * 8;
    int jg = jbase + row;
    short8 vv = {};
    if ((unsigned)jg < (unsigned)T_)
      vv = *(const short8*)(QKV + ((size_t)(b * T_ + jg)) * 1536 + 1024 + h * DH_ + d0);
#pragma unroll
    for (int q = 0; q < 8; ++q) {
      int d = d0 + q;
      Vt[d * 128 + SW8(d, row >> 3) * 8 + (row & 7)] = (unsigned short)vv[q];
    }
  }
  short8 qf[2];
#pragma unroll
  for (int ks = 0; ks < 2; ++ks)
    qf[ks] = *(const short8*)(QKV + ((size_t)(b * T_ + q0 + w * 16 + (l & 15))) * 1536
                              + h * DH_ + ks * 32 + (l >> 4) * 8);
  __syncthreads();

  f32x4 sacc[8] = {};
  __builtin_amdgcn_s_setprio(1);
#pragma unroll
  for (int jt = 0; jt < 8; ++jt) {
#pragma unroll
    for (int ks = 0; ks < 2; ++ks) {
      int row = jt * 16 + (l & 15);
      int sl = ks * 4 + (l >> 4);
      short8 kf = *(const short8*)(Ks + row * 64 + SW8(row, sl) * 8);
      sacc[jt] = __builtin_amdgcn_mfma_f32_16x16x32_bf16(qf[ks], kf, sacc[jt], 0, 0, 0);
    }
  }
  __builtin_amdgcn_s_setprio(0);

  const float scale = 0.125f;
  int qgl0 = q0 + w * 16 + ((l >> 4) << 2);
  int jl = jbase + (l & 15);
  float m4[4] = {-3.0e38f, -3.0e38f, -3.0e38f, -3.0e38f};
#pragma unroll
  for (int jt = 0; jt < 8; ++jt) {
#pragma unroll
    for (int r = 0; r < 4; ++r) {
      float s = sacc[jt][r] * scale;
      int jg = jl + jt * 16;
      int dd = jg - (qgl0 + r);
      bool ok = ((unsigned)jg < (unsigned)T_) && (dd <= 32) && (dd >= -32);
      s = ok ? s : -3.0e38f;
      sacc[jt][r] = s;
      m4[r] = fmaxf(m4[r], s);
    }
  }
#pragma unroll
  for (int r = 0; r < 4; ++r) {
    m4[r] = fmaxf(m4[r], __shfl_xor(m4[r], 1, 64));
    m4[r] = fmaxf(m4[r], __shfl_xor(m4[r], 2, 64));
    m4[r] = fmaxf(m4[r], __shfl_xor(m4[r], 4, 64));
    m4[r] = fmaxf(m4[r], __shfl_xor(m4[r], 8, 64));
  }
  float sum4[4] = {0.f, 0.f, 0.f, 0.f};
#pragma unroll
  for (int jt = 0; jt < 8; ++jt) {
#pragma unroll
    for (int r = 0; r < 4; ++r) {
      float e = __expf(sacc[jt][r] - m4[r]);
      sum4[r] += e;
      int qrow = w * 16 + ((l >> 4) << 2) + r;
      int j = jt * 16 + (l & 15);
      Ps[qrow * 128 + SW8(qrow, j >> 3) * 8 + (j & 7)] = f2bf(e);
    }
  }
#pragma unroll
  for (int r = 0; r < 4; ++r) {
    sum4[r] += __shfl_xor(sum4[r], 1, 64);
    sum4[r] += __shfl_xor(sum4[r], 2, 64);
    sum4[r] += __shfl_xor(sum4[r], 4, 64);
    sum4[r] += __shfl_xor(sum4[r], 8, 64);
    sum4[r] = __builtin_amdgcn_rcpf(sum4[r]);
  }

  f32x4 oacc[4] = {};
  __builtin_amdgcn_s_setprio(1);
#pragma unroll
  for (int ks = 0; ks < 4; ++ks) {
    int prow = w * 16 + (l & 15);
    int sl = ks * 4 + (l >> 4);
    short8 pf = *(const short8*)(Ps + prow * 128 + SW8(prow, sl) * 8);
#pragma unroll
    for (int dt = 0; dt < 4; ++dt) {
      int vrow = dt * 16 + (l & 15);
      short8 vf = *(const short8*)(Vt + vrow * 128 + SW8(vrow, sl) * 8);
      oacc[dt] = __builtin_amdgcn_mfma_f32_16x16x32_bf16(pf, vf, oacc[dt], 0, 0, 0);
    }
  }
  __builtin_amdgcn_s_setprio(0);
#pragma unroll
  for (int dt = 0; dt < 4; ++dt) {
#pragma unroll
    for (int r = 0; r < 4; ++r) {
      int qg = q0 + w * 16 + ((l >> 4) << 2) + r;
      int d = dt * 16 + (l & 15);
      O[((size_t)(b * T_ + qg)) * D_ + h * DH_ + d] = f2bf(oacc[dt][r] * sum4[r]);
    }
  }
}

// ---------------------------------------------------------------- depthwise conv k=31, 2 channels/thread, + GN partials
#define TT_ 16
__global__ __launch_bounds__(256) void dwconv_kernel(const unsigned short* __restrict__ X,
    const float* __restrict__ w, const float* __restrict__ bias,
    unsigned short* __restrict__ Y, float* __restrict__ red)
{
  int t = threadIdx.x;
  int gid = blockIdx.x;              // B * (T/16) * (EC/512) = 1024
  int ecb = gid & 1;
  int tt  = (gid >> 1) & 63;
  int b   = gid >> 7;
  int e0 = ecb * 512 + t * 2;
  int t0 = tt * TT_;
  const unsigned short* xp = X + (size_t)b * T_ * EC_ + e0;

  float wr0[KW_], wr1[KW_];
#pragma unroll
  for (int k = 0; k < KW_; ++k) { wr0[k] = w[e0 * KW_ + k]; wr1[k] = w[(e0 + 1) * KW_ + k]; }
  float out0[TT_], out1[TT_];
  float bv0 = bias[e0], bv1 = bias[e0 + 1];
#pragma unroll
  for (int i = 0; i < TT_; ++i) { out0[i] = bv0; out1[i] = bv1; }

#pragma unroll
  for (int j = 0; j < TT_ + KW_ - 1; ++j) {
    int tj = t0 - 15 + j;
    float x0 = 0.f, x1 = 0.f;
    if ((unsigned)tj < (unsigned)T_) {
      ushort2v u = *(const ushort2v*)(xp + (size_t)tj * EC_);
      x0 = bf2f(u.x); x1 = bf2f(u.y);
    }
#pragma unroll
    for (int i = 0; i < TT_; ++i) {
      int k = j - i;
      if (k >= 0 && k < KW_) {
        out0[i] = fmaf(x0, wr0[k], out0[i]);
        out1[i] = fmaf(x1, wr1[k], out1[i]);
      }
    }
  }
  unsigned short* yp = Y + ((size_t)b * T_ + t0) * EC_ + e0;
  float s = 0.f, s2 = 0.f;
#pragma unroll
  for (int i = 0; i < TT_; ++i) {
    ushort2v o; o.x = f2bf(out0[i]); o.y = f2bf(out1[i]);
    *(ushort2v*)(yp + (size_t)i * EC_) = o;
    s += out0[i] + out1[i];
    s2 += out0[i] * out0[i] + out1[i] * out1[i];
  }
#pragma unroll
  for (int off = 32; off; off >>= 1) {
    s  += __shfl_down(s,  off, 64);
    s2 += __shfl_down(s2, off, 64);
  }
  __shared__ float rs[4], rq[4];
  if ((t & 63) == 0) { rs[t >> 6] = s; rq[t >> 6] = s2; }
  __syncthreads();
  if (t == 0) {
    int loc = gid & 127;
    red[(b * 128 + loc) * 2]     = rs[0] + rs[1] + rs[2] + rs[3];
    red[(b * 128 + loc) * 2 + 1] = rq[0] + rq[1] + rq[2] + rq[3];
  }
}

// ---------------------------------------------------------------- GN stats (128 partials/sample)
__global__ __launch_bounds__(256) void gn_stats_kernel(const float* __restrict__ partial,
                                                       float* __restrict__ stats)
{
  int b = blockIdx.x, t = threadIdx.x;
  float s = 0.f, s2 = 0.f;
  if (t < 128) {
    s  = partial[b * 256 + t * 2];
    s2 = partial[b * 256 + t * 2 + 1];
  }
#pragma unroll
  for (int off = 32; off; off >>= 1) {
    s  += __shfl_down(s,  off, 64);
    s2 += __shfl_down(s2, off, 64);
  }
  __shared__ float rs[4], rq[4];
  if ((t & 63) == 0) { rs[t >> 6] = s; rq[t >> 6] = s2; }
  __syncthreads();
  if (t == 0) {
    float S = rs[0] + rs[1] + rs[2] + rs[3];
    float S2 = rq[0] + rq[1] + rq[2] + rq[3];
    const float n = (float)(T_ * EC_);
    float mean = S / n;
    float var  = S2 / n - mean * mean;
    stats[b * 2]     = mean;
    stats[b * 2 + 1] = __builtin_amdgcn_rsqf(var + 1e-5f);
  }
}

// reads bf16 conv-out, writes silu(gn(..)) bf16 -- 8 elems/thread
__global__ __launch_bounds__(256) void gn_apply_kernel(const unsigned short* __restrict__ X,
    const float* __restrict__ stats, const float* __restrict__ g, const float* __restrict__ bb,
    unsigned short* __restrict__ out)
{
  int idx = blockIdx.x * 256 + threadIdx.x;   // 8-elem chunk index over [B,T,EC]
  int e8 = (idx & 127) << 3;
  int bt = idx >> 7;
  int b  = bt >> 10;
  float mean = stats[b * 2], rstd = stats[b * 2 + 1];
  short8 v = *(const short8*)(X + (size_t)idx * 8);
  float4 g0 = *(const float4*)(g + e8);
  float4 g1 = *(const float4*)(g + e8 + 4);
  float4 b0 = *(const float4*)(bb + e8);
  float4 b1 = *(const float4*)(bb + e8 + 4);
  float gg[8] = {g0.x, g0.y, g0.z, g0.w, g1.x, g1.y, g1.z, g1.w};
  float bv[8] = {b0.x, b0.y, b0.z, b0.w, b1.x, b1.y, b1.z, b1.w};
  short8 o;
#pragma unroll
  for (int j = 0; j < 8; ++j) {
    float u = (bf2f((unsigned short)v[j]) - mean) * rstd * gg[j] + bv[j];
    o[j] = (short)f2bf(u * sigm(u));
  }
  *(short8*)(out + (size_t)idx * 8) = o;
}

// ---------------------------------------------------------------- launch
extern "C" void kernel_launch(void* const* d_in, const int* in_sizes, int n_in,
                              void* d_out, int out_size, void* d_ws, size_t ws_size,
                              hipStream_t stream)
{
  const float* in_x      = (const float*)d_in[0];
  const float* ffn1_ln_g = (const float*)d_in[1];
  const float* ffn1_ln_b = (const float*)d_in[2];
  const float* ffn1_w1   = (const float*)d_in[3];
  const float* ffn1_b1   = (const float*)d_in[4];
  const float* ffn1_w2   = (const float*)d_in[5];
  const float* ffn1_b2   = (const float*)d_in[6];
  const float* attn_ln_g = (const float*)d_in[7];
  const float* attn_ln_b = (const float*)d_in[8];
  const float* qkv_w     = (const float*)d_in[9];
  const float* qkv_b     = (const float*)d_in[10];
  const float* outp_w    = (const float*)d_in[11];
  const float* outp_b    = (const float*)d_in[12];
  const float* conv_ln_g = (const float*)d_in[13];
  const float* conv_ln_b = (const float*)d_in[14];
  const float* pw1_w     = (const float*)d_in[15];
  const float* pw1_b     = (const float*)d_in[16];
  const float* dw_w      = (const float*)d_in[17];
  const float* dw_b      = (const float*)d_in[18];
  const float* gn_g      = (const float*)d_in[19];
  const float* gn_b      = (const float*)d_in[20];
  const float* pw2_w     = (const float*)d_in[21];
  const float* pw2_b     = (const float*)d_in[22];
  const float* ffn2_ln_g = (const float*)d_in[23];
  const float* ffn2_ln_b = (const float*)d_in[24];
  const float* ffn2_w1   = (const float*)d_in[25];
  const float* ffn2_b1   = (const float*)d_in[26];
  const float* ffn2_w2   = (const float*)d_in[27];
  const float* ffn2_b2   = (const float*)d_in[28];
  const float* blk_ln_g  = (const float*)d_in[29];
  const float* blk_ln_b  = (const float*)d_in[30];
  const float* fin_ln_g  = (const float*)d_in[31];
  const float* fin_ln_b  = (const float*)d_in[32];

  char* p = (char*)d_ws;
  unsigned short* x    = (unsigned short*)p; p += (size_t)ROWS * D_ * 2;   // bf16 residual
  unsigned short* big3 = (unsigned short*)p; p += (size_t)ROWS * EC_ * 2;  // conv out bf16
  float* red  = (float*)p;          p += 8192 * 4;
  unsigned short* abuf  = (unsigned short*)p; p += (size_t)ROWS * D_ * 2;
  unsigned short* inner = (unsigned short*)p; p += (size_t)ROWS * FF_ * 2;
  unsigned short* big2  = (unsigned short*)p; p += (size_t)ROWS * EC_ * 2;
  unsigned short* wt_w1a = (unsigned short*)p; p += (size_t)L_ * D_ * FF_ * 2;
  unsigned short* wt_w1b = (unsigned short*)p; p += (size_t)L_ * FF_ * D_ * 2;
  unsigned short* wt_qkv = (unsigned short*)p; p += (size_t)L_ * D_ * 1536 * 2;
  unsigned short* wt_out = (unsigned short*)p; p += (size_t)L_ * D_ * D_ * 2;
  unsigned short* wt_pw1 = (unsigned short*)p; p += (size_t)L_ * D_ * 2048 * 2;
  unsigned short* wt_pw2 = (unsigned short*)p; p += (size_t)L_ * EC_ * D_ * 2;
  unsigned short* wt_w2a = (unsigned short*)p; p += (size_t)L_ * D_ * FF_ * 2;
  unsigned short* wt_w2b = (unsigned short*)p; p += (size_t)L_ * FF_ * D_ * 2;
  float* stats = red + 4096;

  dim3 blk256(256);
  // fused initial convert + first FFN1 LN
  cvt_ln_kernel<<<ROWS/4, blk256, 0, stream>>>(in_x, ffn1_ln_g, ffn1_ln_b, x, abuf);

  wtr_kernel<<<dim3(FF_/32,  D_/32,  L_), blk256, 0, stream>>>(ffn1_w1, wt_w1a, D_, FF_);
  wtr_kernel<<<dim3(D_/32,   FF_/32, L_), blk256, 0, stream>>>(ffn1_w2, wt_w1b, FF_, D_);
  wtr_kernel<<<dim3(1536/32, D_/32,  L_), blk256, 0, stream>>>(qkv_w,   wt_qkv, D_, 1536);
  wtr_kernel<<<dim3(D_/32,   D_/32,  L_), blk256, 0, stream>>>(outp_w,  wt_out, D_, D_);
  wtr_kernel<<<dim3(2048/32, D_/32,  L_), blk256, 0, stream>>>(pw1_w,   wt_pw1, D_, 2048);
  wtr_kernel<<<dim3(D_/32,   EC_/32, L_), blk256, 0, stream>>>(pw2_w,   wt_pw2, EC_, D_);
  wtr_kernel<<<dim3(FF_/32,  D_/32,  L_), blk256, 0, stream>>>(ffn2_w1, wt_w2a, D_, FF_);
  wtr_kernel<<<dim3(D_/32,   FF_/32, L_), blk256, 0, stream>>>(ffn2_w2, wt_w2b, FF_, D_);

  for (int l = 0; l < L_; ++l) {
    // ---- FFN1 ----
    gemm_mfma<1><<<dim3(FF_/128, ROWS/128), blk256, 0, stream>>>(
        abuf, wt_w1a + (size_t)l*D_*FF_, ffn1_b1 + l*FF_, inner, FF_, D_);
    gemm_res64<<<dim3(D_/128, ROWS/64), blk256, 0, stream>>>(
        inner, wt_w1b + (size_t)l*FF_*D_, ffn1_b2 + l*D_, x, x, D_, FF_, 0.5f);

    // ---- local windowed MHSA ----
    ln_bf16_kernel<<<ROWS/4, blk256, 0, stream>>>(x, attn_ln_g + l*D_, attn_ln_b + l*D_, abuf);
    gemm_mfma<0><<<dim3(1536/128, ROWS/128), blk256, 0, stream>>>(
        abuf, wt_qkv + (size_t)l*D_*1536, qkv_b + l*1536, inner, 1536, D_);
    attn_kernel<<<dim3(T_/64, H_, B_), blk256, 0, stream>>>(inner, abuf);
    gemm_res64<<<dim3(D_/128, ROWS/64), blk256, 0, stream>>>(
        abuf, wt_out + (size_t)l*D_*D_, outp_b + l*D_, x, x, D_, D_, 1.0f);

    // ---- conv module (pw1 + GLU fused) ----
    ln_bf16_kernel<<<ROWS/4, blk256, 0, stream>>>(x, conv_ln_g + l*D_, conv_ln_b + l*D_, abuf);
    gemm_mfma<3><<<dim3(EC_/64, ROWS/128), blk256, 0, stream>>>(
        abuf, wt_pw1 + (size_t)l*D_*2048, pw1_b + l*2048, big2, EC_, D_);
    dwconv_kernel<<<B_ * (T_/TT_) * (EC_/512), blk256, 0, stream>>>(
        big2, dw_w + (size_t)l*EC_*KW_, dw_b + l*EC_, big3, red);
    gn_stats_kernel<<<B_, blk256, 0, stream>>>(red, stats);
    gn_apply_kernel<<<(ROWS * EC_ / 8) / 256, blk256, 0, stream>>>(
        big3, stats, gn_g + l*EC_, gn_b + l*EC_, big2);
    gemm_res64<<<dim3(D_/128, ROWS/64), blk256, 0, stream>>>(
        big2, wt_pw2 + (size_t)l*EC_*D_, pw2_b + l*D_, x, x, D_, EC_, 1.0f);

    // ---- FFN2 ----
    ln_bf16_kernel<<<ROWS/4, blk256, 0, stream>>>(x, ffn2_ln_g + l*D_, ffn2_ln_b + l*D_, abuf);
    gemm_mfma<1><<<dim3(FF_/128, ROWS/128), blk256, 0, stream>>>(
        abuf, wt_w2a + (size_t)l*D_*FF_, ffn2_b1 + l*FF_, inner, FF_, D_);
    gemm_res64<<<dim3(D_/128, ROWS/64), blk256, 0, stream>>>(
        inner, wt_w2b + (size_t)l*FF_*D_, ffn2_b2 + l*D_, x, x, D_, FF_, 0.5f);

    // ---- boundary: blk LN fused with next LN ----
    if (l < L_ - 1) {
      ln_dual_kernel<true><<<ROWS/4, blk256, 0, stream>>>(
          x, blk_ln_g + l*D_, blk_ln_b + l*D_,
          ffn1_ln_g + (l+1)*D_, ffn1_ln_b + (l+1)*D_, x, abuf);
    } else {
      ln_dual_kernel<false><<<ROWS/4, blk256, 0, stream>>>(
          x, blk_ln_g + l*D_, blk_ln_b + l*D_, fin_ln_g, fin_ln_b, x, d_out);
    }
  }
}